// Round 7
// baseline (311.019 us; speedup 1.0000x reference)
//
#include <hip/hip_runtime.h>
#include <math.h>

// ---------------------------------------------------------------------------
// CausalSelfAttention  B=4 T=2048 C=1024 H=16 D=64, fp32 in/out.
// Round 7: GEMM LDS bank-conflict fix (XOR swizzle, same scheme as attn).
//   rocprof r6: gemm_bf16 106us, MfmaUtil 20%, SQ_LDS_BANK_CONFLICT 6.3M ->
//   8-way conflict on ds_read_b128 fragment reads (row stride 64B=16 banks).
//   Swizzle 16B slots: physical slot s of row r holds logical slot
//   s ^ ((r>>1)&3); applied on global src addr (DMA dest must stay linear).
//   Attention kernel unchanged (r6 cold-dispatch row was profile pollution).
// ---------------------------------------------------------------------------

typedef unsigned short ushort_t;
typedef __attribute__((ext_vector_type(8))) short bf16x8;   // 8 bf16 (4 VGPRs)
typedef __attribute__((ext_vector_type(4))) float f32x4;

#define MFMA16(a, b, c) __builtin_amdgcn_mfma_f32_16x16x32_bf16((a), (b), (c), 0, 0, 0)

#define CP_ASYNC16(lds, gp)                                                        \
    __builtin_amdgcn_global_load_lds(                                              \
        (const __attribute__((address_space(1))) void*)(gp),                       \
        (__attribute__((address_space(3))) void*)(lds), 16, 0, 0)

#define SCALE2 0.1803368801111204f   // 0.125 * log2(e): softmax in base-2

__device__ __forceinline__ ushort_t bf16r(float x) {
    unsigned int u = __float_as_uint(x);
    u += 0x7FFFu + ((u >> 16) & 1u);      // round-to-nearest-even
    return (ushort_t)(u >> 16);
}

// ---------------- prologue kernels ----------------

__global__ __launch_bounds__(256) void cast_f32_bf16(const float4* __restrict__ src,
                                                     ushort4* __restrict__ dst) {
    int i = blockIdx.x * 256 + threadIdx.x;
    float4 v = src[i];
    ushort4 o;
    o.x = bf16r(v.x); o.y = bf16r(v.y); o.z = bf16r(v.z); o.w = bf16r(v.w);
    dst[i] = o;
}

// src fp32 [R][Cc] -> dst bf16 [Cc][R]
__global__ __launch_bounds__(256) void transpose_cast(const float* __restrict__ src,
                                                      ushort_t* __restrict__ dst,
                                                      int R, int Cc) {
    __shared__ float tile[32][33];
    const int tx = threadIdx.x, ty = threadIdx.y;       // block (32,8)
    const int c0 = blockIdx.x * 32, r0 = blockIdx.y * 32;
#pragma unroll
    for (int i = 0; i < 4; ++i)
        tile[ty + i * 8][tx] = src[(size_t)(r0 + ty + i * 8) * Cc + c0 + tx];
    __syncthreads();
#pragma unroll
    for (int i = 0; i < 4; ++i)
        dst[(size_t)(c0 + ty + i * 8) * R + r0 + tx] = bf16r(tile[tx][ty + i * 8]);
}

// ---------------- MFMA GEMM: C[M,N] = A[M,K] @ Bt[N,K]^T ----------------
// 128x128 tile, BK=32, 256 threads (4 waves 2x2), 4x4 16x16 tiles per wave.
// LDS 16B slots XOR-swizzled (slot ^ ((row>>1)&3)) -> 0 bank conflicts.
// mode 0: scatter bf16 into Qh (pre-scaled!) / Kh / Vt.  mode 1: fp32 Cout.
__global__ __launch_bounds__(256)
void gemm_bf16(const ushort_t* __restrict__ A, const ushort_t* __restrict__ Bt,
               int K, int mode,
               ushort_t* __restrict__ Qh, ushort_t* __restrict__ Kh,
               ushort_t* __restrict__ Vt, float* __restrict__ Cout) {
    __shared__ ushort_t As[128 * 32];
    __shared__ ushort_t Bs[128 * 32];
    const int tid = threadIdx.x;
    const int l = tid & 63, w = tid >> 6;
    const int lm = l & 15, lq = l >> 4;
    const int wm = w >> 1, wn = w & 1;
    const int row0 = blockIdx.y * 128, col0 = blockIdx.x * 128;
    const f32x4 zero4 = {0.f, 0.f, 0.f, 0.f};
    const int lqs8 = (lq ^ ((lm >> 1) & 3)) * 8;   // swizzled fragment slot

    f32x4 acc[4][4];
#pragma unroll
    for (int i = 0; i < 4; ++i)
#pragma unroll
        for (int j = 0; j < 4; ++j) acc[i][j] = zero4;

    // staging: thread -> row srow (0..63 / 64..127), 16B slot; swizzle on src
    const int srow = tid >> 2, slot = tid & 3;
    const int soff = (slot ^ ((srow >> 1) & 3)) * 8;
    const ushort_t* ga0 = A + (size_t)(row0 + srow) * K + soff;
    const ushort_t* ga1 = ga0 + (size_t)64 * K;
    const ushort_t* gb0 = Bt + (size_t)(col0 + srow) * K + soff;
    const ushort_t* gb1 = gb0 + (size_t)64 * K;
    ushort_t* la0 = As + tid * 8;
    ushort_t* la1 = As + (tid + 256) * 8;
    ushort_t* lb0 = Bs + tid * 8;
    ushort_t* lb1 = Bs + (tid + 256) * 8;

    const int aoffb = (wm * 64 + lm) * 32 + lqs8;
    const int boffb = (wn * 64 + lm) * 32 + lqs8;

    for (int k0 = 0; k0 < K; k0 += 32) {
        CP_ASYNC16(la0, ga0); CP_ASYNC16(la1, ga1);
        CP_ASYNC16(lb0, gb0); CP_ASYNC16(lb1, gb1);
        ga0 += 32; ga1 += 32; gb0 += 32; gb1 += 32;
        __syncthreads();
        bf16x8 af[4], bfr[4];
#pragma unroll
        for (int i = 0; i < 4; ++i)
            af[i] = *(const bf16x8*)(As + aoffb + i * (16 * 32));
#pragma unroll
        for (int j = 0; j < 4; ++j)
            bfr[j] = *(const bf16x8*)(Bs + boffb + j * (16 * 32));
#pragma unroll
        for (int i = 0; i < 4; ++i)
#pragma unroll
            for (int j = 0; j < 4; ++j)
                acc[i][j] = MFMA16(af[i], bfr[j], acc[i][j]);
        __syncthreads();
    }

#pragma unroll
    for (int i = 0; i < 4; ++i) {
#pragma unroll
        for (int j = 0; j < 4; ++j) {
#pragma unroll
            for (int reg = 0; reg < 4; ++reg) {
                const int rr = row0 + wm * 64 + i * 16 + lq * 4 + reg;
                const int cc = col0 + wn * 64 + j * 16 + lm;
                const float v = acc[i][j][reg];
                if (mode == 1) {
                    Cout[(size_t)rr * 1024 + cc] = v;
                } else {
                    const int b = rr >> 11, t = rr & 2047;
                    if (cc < 1024) {
                        const int h = cc >> 6, d = cc & 63;
                        Qh[((size_t)(b * 16 + h) * 2048 + t) * 64 + d] =
                            bf16r(v * SCALE2);          // fold softmax scale
                    } else if (cc < 2048) {
                        const int c2 = cc - 1024, h = c2 >> 6, d = c2 & 63;
                        Kh[((size_t)(b * 16 + h) * 2048 + t) * 64 + d] = bf16r(v);
                    } else {
                        const int c2 = cc - 2048, h = c2 >> 6, d = c2 & 63;
                        Vt[((size_t)(b * 16 + h) * 64 + d) * 2048 + t] = bf16r(v);
                    }
                }
            }
        }
    }
}

// ---------------- flash attention, MFMA, no-max softmax ----------------
// grid (64 bh, 16 pairs), 256 threads. Block handles q-tiles qbA=pr, qbB=31-pr
// against ONE k-stream 0..qbB; k-tiles <= qbA feed both q-frags (kf shared).
// LDS: Ks 2x8KB dbuf + Vs 2x8KB dbuf + Ps 4x2KB = 40960 B -> 4 blocks/CU.
// 16B slot s of row r holds logical slot s ^ ((r>>1)&3): 0 bank conflicts.
__global__ __launch_bounds__(256, 4)
void attn_mfma(const ushort_t* __restrict__ Qh, const ushort_t* __restrict__ Kh,
               const ushort_t* __restrict__ Vt, ushort_t* __restrict__ Y) {
    __shared__ ushort_t Ks[2][4096];
    __shared__ ushort_t Vs[2][4096];
    __shared__ ushort_t Ps[4][1024];
    const int tid = threadIdx.x, l = tid & 63, w = tid >> 6;
    const int lm = l & 15, lq = l >> 4;
    const int bh = blockIdx.x;                 // same bh -> shared L2 for K/V
    const int pr = blockIdx.y;                 // pair 0..15
    const int qbA = pr, qbB = 31 - pr;
    const int b = bh >> 4, h = bh & 15;
    const f32x4 zero4 = {0.f, 0.f, 0.f, 0.f};
    const short oneb = (short)0x3F80;          // bf16 1.0
    const bf16x8 onesf = {oneb, oneb, oneb, oneb, oneb, oneb, oneb, oneb};
    const int lqs8 = (lq ^ ((lm >> 1) & 3)) * 8;   // swizzled 16B slot offset

    // Q fragments for both tiles (Q pre-scaled by SCALE2)
    bf16x8 qf[2][2];
    {
        const ushort_t* qA = Qh + ((size_t)bh * 2048 + qbA * 64 + w * 16 + lm) * 64 + lq * 8;
        const ushort_t* qB = Qh + ((size_t)bh * 2048 + qbB * 64 + w * 16 + lm) * 64 + lq * 8;
        qf[0][0] = *(const bf16x8*)(qA);
        qf[0][1] = *(const bf16x8*)(qA + 32);
        qf[1][0] = *(const bf16x8*)(qB);
        qf[1][1] = *(const bf16x8*)(qB + 32);
    }

    f32x4 O[2][4], Ol[2];
#pragma unroll
    for (int q = 0; q < 2; ++q) {
        Ol[q] = zero4;
#pragma unroll
        for (int i = 0; i < 4; ++i) O[q][i] = zero4;
    }

    // DMA staging: thread -> row srow, 16B slot; swizzle applied on global src
    const int srow = tid >> 2, slot = tid & 3;
    const int srcoff = ((slot ^ ((srow >> 1) & 3)) * 8);
    const ushort_t* gKr = Kh + ((size_t)bh * 2048 + srow) * 64 + srcoff;  // +jb*4096
    const ushort_t* gVr = Vt + ((size_t)bh * 64 + srow) * 2048 + srcoff;  // +jb*64
    ushort_t* Pw = Ps[w];

    auto prefetch = [&](int jbn, int dbuf) {
        const ushort_t* gk = gKr + (size_t)jbn * 4096;
        const ushort_t* gv = gVr + jbn * 64;
        CP_ASYNC16(&Ks[dbuf][tid * 8], gk);
        CP_ASYNC16(&Ks[dbuf][2048 + tid * 8], gk + 32);
        CP_ASYNC16(&Vs[dbuf][tid * 8], gv);
        CP_ASYNC16(&Vs[dbuf][2048 + tid * 8], gv + 32);
    };

    // one q-frag against the k-tile in Ks/Vs[buf]; kf passed in (shared)
    auto process = [&](const bf16x8 (&kf)[4][2], const ushort_t* Vb,
                       const bf16x8 (&qfr)[2], f32x4 (&Or)[4], f32x4& Olr,
                       bool diag) {
        f32x4 sf[4];
#pragma unroll
        for (int n = 0; n < 4; ++n) {
            f32x4 s_acc = zero4;
            s_acc = MFMA16(qfr[0], kf[n][0], s_acc);
            s_acc = MFMA16(qfr[1], kf[n][1], s_acc);
            sf[n] = s_acc;
        }

        // p = exp2(s) directly (no max); mask only on diagonal tile
        float p[4][4];
#pragma unroll
        for (int n = 0; n < 4; ++n)
#pragma unroll
            for (int reg = 0; reg < 4; ++reg)
                p[n][reg] = __builtin_amdgcn_exp2f(sf[n][reg]);
        if (diag) {
#pragma unroll
            for (int n = 0; n < 4; ++n) {
                const int key = n * 16 + lm;
#pragma unroll
                for (int reg = 0; reg < 4; ++reg) {
                    const int qloc = w * 16 + lq * 4 + reg;
                    if (key > qloc) p[n][reg] = 0.f;
                }
            }
        }

        // P -> LDS (C-layout -> A-operand layout), swizzled, biased-round bf16
#pragma unroll
        for (int n = 0; n < 4; ++n) {
            const int ch = n >> 1, nn = n & 1;
#pragma unroll
            for (int reg = 0; reg < 4; ++reg) {
                const int r = lq * 4 + reg;
                const int ss = (nn * 2 + (lm >> 3)) ^ ((2 * lq + (reg >> 1)) & 3);
                const unsigned int u = __float_as_uint(p[n][reg]) + 0x8000u;
                Pw[ch * 512 + r * 32 + ss * 8 + (lm & 7)] = (ushort_t)(u >> 16);
            }
        }
        const bf16x8 pf0 = *(const bf16x8*)(Pw + lm * 32 + lqs8);
        const bf16x8 pf1 = *(const bf16x8*)(Pw + 512 + lm * 32 + lqs8);

#pragma unroll
        for (int dn = 0; dn < 4; ++dn) {
            const bf16x8 vf0 = *(const bf16x8*)(Vb + (dn * 16 + lm) * 32 + lqs8);
            const bf16x8 vf1 = *(const bf16x8*)(Vb + 2048 + (dn * 16 + lm) * 32 + lqs8);
            Or[dn] = MFMA16(pf0, vf0, Or[dn]);
            Or[dn] = MFMA16(pf1, vf1, Or[dn]);
        }
        Olr = MFMA16(pf0, onesf, Olr);
        Olr = MFMA16(pf1, onesf, Olr);
    };

    prefetch(0, 0);
    for (int jb = 0; jb <= qbB; ++jb) {
        const int buf = jb & 1;
        __syncthreads();                   // own DMA drained; prev buf free
        if (jb < qbB) prefetch(jb + 1, buf ^ 1);

        const ushort_t* Kb = Ks[buf];
        const ushort_t* Vb = Vs[buf];
        bf16x8 kf[4][2];
#pragma unroll
        for (int n = 0; n < 4; ++n) {
            kf[n][0] = *(const bf16x8*)(Kb + (n * 16 + lm) * 32 + lqs8);
            kf[n][1] = *(const bf16x8*)(Kb + 2048 + (n * 16 + lm) * 32 + lqs8);
        }

        process(kf, Vb, qf[1], O[1], Ol[1], jb == qbB);          // frag B
        if (jb <= qbA)
            process(kf, Vb, qf[0], O[0], Ol[0], jb == qbA);      // frag A
    }

    // epilogue: y[b*2048+t][h*64+d] bf16
#pragma unroll
    for (int qs = 0; qs < 2; ++qs) {
        const int tq = (qs ? qbB : qbA) * 64;
#pragma unroll
        for (int reg = 0; reg < 4; ++reg) {
            const float inv = 1.f / Ol[qs][reg];
            const size_t row = (size_t)b * 2048 + tq + w * 16 + lq * 4 + reg;
#pragma unroll
            for (int dn = 0; dn < 4; ++dn)
                Y[row * 1024 + h * 64 + dn * 16 + lm] = bf16r(O[qs][dn][reg] * inv);
        }
    }
}

// ---------------- launch ----------------

extern "C" void kernel_launch(void* const* d_in, const int* in_sizes, int n_in,
                              void* d_out, int out_size, void* d_ws, size_t ws_size,
                              hipStream_t stream) {
    const float* x      = (const float*)d_in[0];   // [8192,1024]
    const float* w_attn = (const float*)d_in[1];   // [1024,3072]
    const float* w_proj = (const float*)d_in[2];   // [1024,1024]
    float* out = (float*)d_out;

    char* ws = (char*)d_ws;
    ushort_t* xb   = (ushort_t*)(ws);                       // 16 MB  [8192][1024]
    ushort_t* watT = (ushort_t*)(ws + 16777216);            // 6 MB   [3072][1024]
    ushort_t* wpjT = (ushort_t*)(ws + 23068672);            // 2 MB   [1024][1024]
    ushort_t* Qh   = (ushort_t*)(ws + 25165824);            // 16 MB  [b,h,t,d] (pre-scaled)
    ushort_t* Kh   = (ushort_t*)(ws + 41943040);            // 16 MB  [b,h,t,d]
    ushort_t* Vt   = (ushort_t*)(ws + 58720256);            // 16 MB  [b,h,d,t]
    ushort_t* Y    = (ushort_t*)(ws + 75497472);            // 16 MB  [8192][1024]

    hipLaunchKernelGGL(cast_f32_bf16, dim3(8192), dim3(256), 0, stream,
                       (const float4*)x, (ushort4*)xb);
    hipLaunchKernelGGL(transpose_cast, dim3(96, 32), dim3(32, 8), 0, stream,
                       w_attn, watT, 1024, 3072);
    hipLaunchKernelGGL(transpose_cast, dim3(32, 32), dim3(32, 8), 0, stream,
                       w_proj, wpjT, 1024, 1024);

    hipLaunchKernelGGL(gemm_bf16, dim3(24, 64), dim3(256), 0, stream,
                       xb, watT, 1024, 0, Qh, Kh, Vt, (float*)nullptr);

    hipLaunchKernelGGL(attn_mfma, dim3(64, 16), dim3(256), 0, stream,
                       Qh, Kh, Vt, Y);

    hipLaunchKernelGGL(gemm_bf16, dim3(8, 64), dim3(256), 0, stream,
                       Y, wpjT, 1024, 1, (ushort_t*)nullptr, (ushort_t*)nullptr,
                       (ushort_t*)nullptr, out);
}

// Round 8
// 298.056 us; speedup vs baseline: 1.0435x; 1.0435x over previous
//
#include <hip/hip_runtime.h>
#include <math.h>

// ---------------------------------------------------------------------------
// CausalSelfAttention  B=4 T=2048 C=1024 H=16 D=64, fp32 in/out.
// Round 8: GEMM double-buffered staging.
//   r7 post-mortem: conflicts->0 changed nothing; the stall is structural --
//   CP_ASYNC(tile k) immediately followed by __syncthreads() exposes the full
//   DMA latency every iteration (~660 cyc/iter vs 77 cyc MFMA). Fix = the
//   same single-barrier dbuf pipeline already proven in attn_mfma (r5):
//   sync -> prefetch k+1 into other buffer -> compute k. LDS 32 KB.
// ---------------------------------------------------------------------------

typedef unsigned short ushort_t;
typedef __attribute__((ext_vector_type(8))) short bf16x8;   // 8 bf16 (4 VGPRs)
typedef __attribute__((ext_vector_type(4))) float f32x4;

#define MFMA16(a, b, c) __builtin_amdgcn_mfma_f32_16x16x32_bf16((a), (b), (c), 0, 0, 0)

#define CP_ASYNC16(lds, gp)                                                        \
    __builtin_amdgcn_global_load_lds(                                              \
        (const __attribute__((address_space(1))) void*)(gp),                       \
        (__attribute__((address_space(3))) void*)(lds), 16, 0, 0)

#define SCALE2 0.1803368801111204f   // 0.125 * log2(e): softmax in base-2

__device__ __forceinline__ ushort_t bf16r(float x) {
    unsigned int u = __float_as_uint(x);
    u += 0x7FFFu + ((u >> 16) & 1u);      // round-to-nearest-even
    return (ushort_t)(u >> 16);
}

// ---------------- prologue kernels ----------------

__global__ __launch_bounds__(256) void cast_f32_bf16(const float4* __restrict__ src,
                                                     ushort4* __restrict__ dst) {
    int i = blockIdx.x * 256 + threadIdx.x;
    float4 v = src[i];
    ushort4 o;
    o.x = bf16r(v.x); o.y = bf16r(v.y); o.z = bf16r(v.z); o.w = bf16r(v.w);
    dst[i] = o;
}

// src fp32 [R][Cc] -> dst bf16 [Cc][R]
__global__ __launch_bounds__(256) void transpose_cast(const float* __restrict__ src,
                                                      ushort_t* __restrict__ dst,
                                                      int R, int Cc) {
    __shared__ float tile[32][33];
    const int tx = threadIdx.x, ty = threadIdx.y;       // block (32,8)
    const int c0 = blockIdx.x * 32, r0 = blockIdx.y * 32;
#pragma unroll
    for (int i = 0; i < 4; ++i)
        tile[ty + i * 8][tx] = src[(size_t)(r0 + ty + i * 8) * Cc + c0 + tx];
    __syncthreads();
#pragma unroll
    for (int i = 0; i < 4; ++i)
        dst[(size_t)(c0 + ty + i * 8) * R + r0 + tx] = bf16r(tile[tx][ty + i * 8]);
}

// ---------------- MFMA GEMM: C[M,N] = A[M,K] @ Bt[N,K]^T ----------------
// 128x128 tile, BK=32, 256 threads (4 waves 2x2), 4x4 16x16 tiles per wave.
// Double-buffered global_load_lds staging, one barrier per K-iter.
// LDS 16B slots XOR-swizzled (slot ^ ((row>>1)&3)) -> 0 bank conflicts.
// mode 0: scatter bf16 into Qh (pre-scaled!) / Kh / Vt.  mode 1: fp32 Cout.
__global__ __launch_bounds__(256)
void gemm_bf16(const ushort_t* __restrict__ A, const ushort_t* __restrict__ Bt,
               int K, int mode,
               ushort_t* __restrict__ Qh, ushort_t* __restrict__ Kh,
               ushort_t* __restrict__ Vt, float* __restrict__ Cout) {
    __shared__ ushort_t As[2][128 * 32];
    __shared__ ushort_t Bs[2][128 * 32];
    const int tid = threadIdx.x;
    const int l = tid & 63, w = tid >> 6;
    const int lm = l & 15, lq = l >> 4;
    const int wm = w >> 1, wn = w & 1;
    const int row0 = blockIdx.y * 128, col0 = blockIdx.x * 128;
    const f32x4 zero4 = {0.f, 0.f, 0.f, 0.f};
    const int lqs8 = (lq ^ ((lm >> 1) & 3)) * 8;   // swizzled fragment slot

    f32x4 acc[4][4];
#pragma unroll
    for (int i = 0; i < 4; ++i)
#pragma unroll
        for (int j = 0; j < 4; ++j) acc[i][j] = zero4;

    // staging: thread -> row srow (0..63 / 64..127), 16B slot; swizzle on src
    const int srow = tid >> 2, slot = tid & 3;
    const int soff = (slot ^ ((srow >> 1) & 3)) * 8;
    const ushort_t* ga0 = A + (size_t)(row0 + srow) * K + soff;
    const ushort_t* ga1 = ga0 + (size_t)64 * K;
    const ushort_t* gb0 = Bt + (size_t)(col0 + srow) * K + soff;
    const ushort_t* gb1 = gb0 + (size_t)64 * K;

    const int aoffb = (wm * 64 + lm) * 32 + lqs8;
    const int boffb = (wn * 64 + lm) * 32 + lqs8;

    auto prefetch = [&](int k0, int dbuf) {
        CP_ASYNC16(&As[dbuf][tid * 8], ga0 + k0);
        CP_ASYNC16(&As[dbuf][(tid + 256) * 8], ga1 + k0);
        CP_ASYNC16(&Bs[dbuf][tid * 8], gb0 + k0);
        CP_ASYNC16(&Bs[dbuf][(tid + 256) * 8], gb1 + k0);
    };

    prefetch(0, 0);
    const int niter = K >> 5;
    for (int it = 0; it < niter; ++it) {
        const int buf = it & 1;
        __syncthreads();                       // drains own DMA for buf
        if (it + 1 < niter) prefetch((it + 1) << 5, buf ^ 1);

        bf16x8 af[4], bfr[4];
#pragma unroll
        for (int i = 0; i < 4; ++i)
            af[i] = *(const bf16x8*)(As[buf] + aoffb + i * (16 * 32));
#pragma unroll
        for (int j = 0; j < 4; ++j)
            bfr[j] = *(const bf16x8*)(Bs[buf] + boffb + j * (16 * 32));
#pragma unroll
        for (int i = 0; i < 4; ++i)
#pragma unroll
            for (int j = 0; j < 4; ++j)
                acc[i][j] = MFMA16(af[i], bfr[j], acc[i][j]);
    }

#pragma unroll
    for (int i = 0; i < 4; ++i) {
#pragma unroll
        for (int j = 0; j < 4; ++j) {
#pragma unroll
            for (int reg = 0; reg < 4; ++reg) {
                const int rr = row0 + wm * 64 + i * 16 + lq * 4 + reg;
                const int cc = col0 + wn * 64 + j * 16 + lm;
                const float v = acc[i][j][reg];
                if (mode == 1) {
                    Cout[(size_t)rr * 1024 + cc] = v;
                } else {
                    const int b = rr >> 11, t = rr & 2047;
                    if (cc < 1024) {
                        const int h = cc >> 6, d = cc & 63;
                        Qh[((size_t)(b * 16 + h) * 2048 + t) * 64 + d] =
                            bf16r(v * SCALE2);          // fold softmax scale
                    } else if (cc < 2048) {
                        const int c2 = cc - 1024, h = c2 >> 6, d = c2 & 63;
                        Kh[((size_t)(b * 16 + h) * 2048 + t) * 64 + d] = bf16r(v);
                    } else {
                        const int c2 = cc - 2048, h = c2 >> 6, d = c2 & 63;
                        Vt[((size_t)(b * 16 + h) * 64 + d) * 2048 + t] = bf16r(v);
                    }
                }
            }
        }
    }
}

// ---------------- flash attention, MFMA, no-max softmax ----------------
// grid (64 bh, 16 pairs), 256 threads. Block handles q-tiles qbA=pr, qbB=31-pr
// against ONE k-stream 0..qbB; k-tiles <= qbA feed both q-frags (kf shared).
// LDS: Ks 2x8KB dbuf + Vs 2x8KB dbuf + Ps 4x2KB = 40960 B -> 4 blocks/CU.
// 16B slot s of row r holds logical slot s ^ ((r>>1)&3): 0 bank conflicts.
__global__ __launch_bounds__(256, 4)
void attn_mfma(const ushort_t* __restrict__ Qh, const ushort_t* __restrict__ Kh,
               const ushort_t* __restrict__ Vt, ushort_t* __restrict__ Y) {
    __shared__ ushort_t Ks[2][4096];
    __shared__ ushort_t Vs[2][4096];
    __shared__ ushort_t Ps[4][1024];
    const int tid = threadIdx.x, l = tid & 63, w = tid >> 6;
    const int lm = l & 15, lq = l >> 4;
    const int bh = blockIdx.x;                 // same bh -> shared L2 for K/V
    const int pr = blockIdx.y;                 // pair 0..15
    const int qbA = pr, qbB = 31 - pr;
    const int b = bh >> 4, h = bh & 15;
    const f32x4 zero4 = {0.f, 0.f, 0.f, 0.f};
    const short oneb = (short)0x3F80;          // bf16 1.0
    const bf16x8 onesf = {oneb, oneb, oneb, oneb, oneb, oneb, oneb, oneb};
    const int lqs8 = (lq ^ ((lm >> 1) & 3)) * 8;   // swizzled 16B slot offset

    // Q fragments for both tiles (Q pre-scaled by SCALE2)
    bf16x8 qf[2][2];
    {
        const ushort_t* qA = Qh + ((size_t)bh * 2048 + qbA * 64 + w * 16 + lm) * 64 + lq * 8;
        const ushort_t* qB = Qh + ((size_t)bh * 2048 + qbB * 64 + w * 16 + lm) * 64 + lq * 8;
        qf[0][0] = *(const bf16x8*)(qA);
        qf[0][1] = *(const bf16x8*)(qA + 32);
        qf[1][0] = *(const bf16x8*)(qB);
        qf[1][1] = *(const bf16x8*)(qB + 32);
    }

    f32x4 O[2][4], Ol[2];
#pragma unroll
    for (int q = 0; q < 2; ++q) {
        Ol[q] = zero4;
#pragma unroll
        for (int i = 0; i < 4; ++i) O[q][i] = zero4;
    }

    // DMA staging: thread -> row srow, 16B slot; swizzle applied on global src
    const int srow = tid >> 2, slot = tid & 3;
    const int srcoff = ((slot ^ ((srow >> 1) & 3)) * 8);
    const ushort_t* gKr = Kh + ((size_t)bh * 2048 + srow) * 64 + srcoff;  // +jb*4096
    const ushort_t* gVr = Vt + ((size_t)bh * 64 + srow) * 2048 + srcoff;  // +jb*64
    ushort_t* Pw = Ps[w];

    auto prefetch = [&](int jbn, int dbuf) {
        const ushort_t* gk = gKr + (size_t)jbn * 4096;
        const ushort_t* gv = gVr + jbn * 64;
        CP_ASYNC16(&Ks[dbuf][tid * 8], gk);
        CP_ASYNC16(&Ks[dbuf][2048 + tid * 8], gk + 32);
        CP_ASYNC16(&Vs[dbuf][tid * 8], gv);
        CP_ASYNC16(&Vs[dbuf][2048 + tid * 8], gv + 32);
    };

    // one q-frag against the k-tile in Ks/Vs[buf]; kf passed in (shared)
    auto process = [&](const bf16x8 (&kf)[4][2], const ushort_t* Vb,
                       const bf16x8 (&qfr)[2], f32x4 (&Or)[4], f32x4& Olr,
                       bool diag) {
        f32x4 sf[4];
#pragma unroll
        for (int n = 0; n < 4; ++n) {
            f32x4 s_acc = zero4;
            s_acc = MFMA16(qfr[0], kf[n][0], s_acc);
            s_acc = MFMA16(qfr[1], kf[n][1], s_acc);
            sf[n] = s_acc;
        }

        // p = exp2(s) directly (no max); mask only on diagonal tile
        float p[4][4];
#pragma unroll
        for (int n = 0; n < 4; ++n)
#pragma unroll
            for (int reg = 0; reg < 4; ++reg)
                p[n][reg] = __builtin_amdgcn_exp2f(sf[n][reg]);
        if (diag) {
#pragma unroll
            for (int n = 0; n < 4; ++n) {
                const int key = n * 16 + lm;
#pragma unroll
                for (int reg = 0; reg < 4; ++reg) {
                    const int qloc = w * 16 + lq * 4 + reg;
                    if (key > qloc) p[n][reg] = 0.f;
                }
            }
        }

        // P -> LDS (C-layout -> A-operand layout), swizzled, biased-round bf16
#pragma unroll
        for (int n = 0; n < 4; ++n) {
            const int ch = n >> 1, nn = n & 1;
#pragma unroll
            for (int reg = 0; reg < 4; ++reg) {
                const int r = lq * 4 + reg;
                const int ss = (nn * 2 + (lm >> 3)) ^ ((2 * lq + (reg >> 1)) & 3);
                const unsigned int u = __float_as_uint(p[n][reg]) + 0x8000u;
                Pw[ch * 512 + r * 32 + ss * 8 + (lm & 7)] = (ushort_t)(u >> 16);
            }
        }
        const bf16x8 pf0 = *(const bf16x8*)(Pw + lm * 32 + lqs8);
        const bf16x8 pf1 = *(const bf16x8*)(Pw + 512 + lm * 32 + lqs8);

#pragma unroll
        for (int dn = 0; dn < 4; ++dn) {
            const bf16x8 vf0 = *(const bf16x8*)(Vb + (dn * 16 + lm) * 32 + lqs8);
            const bf16x8 vf1 = *(const bf16x8*)(Vb + 2048 + (dn * 16 + lm) * 32 + lqs8);
            Or[dn] = MFMA16(pf0, vf0, Or[dn]);
            Or[dn] = MFMA16(pf1, vf1, Or[dn]);
        }
        Olr = MFMA16(pf0, onesf, Olr);
        Olr = MFMA16(pf1, onesf, Olr);
    };

    prefetch(0, 0);
    for (int jb = 0; jb <= qbB; ++jb) {
        const int buf = jb & 1;
        __syncthreads();                   // own DMA drained; prev buf free
        if (jb < qbB) prefetch(jb + 1, buf ^ 1);

        const ushort_t* Kb = Ks[buf];
        const ushort_t* Vb = Vs[buf];
        bf16x8 kf[4][2];
#pragma unroll
        for (int n = 0; n < 4; ++n) {
            kf[n][0] = *(const bf16x8*)(Kb + (n * 16 + lm) * 32 + lqs8);
            kf[n][1] = *(const bf16x8*)(Kb + 2048 + (n * 16 + lm) * 32 + lqs8);
        }

        process(kf, Vb, qf[1], O[1], Ol[1], jb == qbB);          // frag B
        if (jb <= qbA)
            process(kf, Vb, qf[0], O[0], Ol[0], jb == qbA);      // frag A
    }

    // epilogue: y[b*2048+t][h*64+d] bf16
#pragma unroll
    for (int qs = 0; qs < 2; ++qs) {
        const int tq = (qs ? qbB : qbA) * 64;
#pragma unroll
        for (int reg = 0; reg < 4; ++reg) {
            const float inv = 1.f / Ol[qs][reg];
            const size_t row = (size_t)b * 2048 + tq + w * 16 + lq * 4 + reg;
#pragma unroll
            for (int dn = 0; dn < 4; ++dn)
                Y[row * 1024 + h * 64 + dn * 16 + lm] = bf16r(O[qs][dn][reg] * inv);
        }
    }
}

// ---------------- launch ----------------

extern "C" void kernel_launch(void* const* d_in, const int* in_sizes, int n_in,
                              void* d_out, int out_size, void* d_ws, size_t ws_size,
                              hipStream_t stream) {
    const float* x      = (const float*)d_in[0];   // [8192,1024]
    const float* w_attn = (const float*)d_in[1];   // [1024,3072]
    const float* w_proj = (const float*)d_in[2];   // [1024,1024]
    float* out = (float*)d_out;

    char* ws = (char*)d_ws;
    ushort_t* xb   = (ushort_t*)(ws);                       // 16 MB  [8192][1024]
    ushort_t* watT = (ushort_t*)(ws + 16777216);            // 6 MB   [3072][1024]
    ushort_t* wpjT = (ushort_t*)(ws + 23068672);            // 2 MB   [1024][1024]
    ushort_t* Qh   = (ushort_t*)(ws + 25165824);            // 16 MB  [b,h,t,d] (pre-scaled)
    ushort_t* Kh   = (ushort_t*)(ws + 41943040);            // 16 MB  [b,h,t,d]
    ushort_t* Vt   = (ushort_t*)(ws + 58720256);            // 16 MB  [b,h,d,t]
    ushort_t* Y    = (ushort_t*)(ws + 75497472);            // 16 MB  [8192][1024]

    hipLaunchKernelGGL(cast_f32_bf16, dim3(8192), dim3(256), 0, stream,
                       (const float4*)x, (ushort4*)xb);
    hipLaunchKernelGGL(transpose_cast, dim3(96, 32), dim3(32, 8), 0, stream,
                       w_attn, watT, 1024, 3072);
    hipLaunchKernelGGL(transpose_cast, dim3(32, 32), dim3(32, 8), 0, stream,
                       w_proj, wpjT, 1024, 1024);

    hipLaunchKernelGGL(gemm_bf16, dim3(24, 64), dim3(256), 0, stream,
                       xb, watT, 1024, 0, Qh, Kh, Vt, (float*)nullptr);

    hipLaunchKernelGGL(attn_mfma, dim3(64, 16), dim3(256), 0, stream,
                       Qh, Kh, Vt, Y);

    hipLaunchKernelGGL(gemm_bf16, dim3(8, 64), dim3(256), 0, stream,
                       Y, wpjT, 1024, 1, (ushort_t*)nullptr, (ushort_t*)nullptr,
                       (ushort_t*)nullptr, out);
}